// Round 5
// baseline (1617.337 us; speedup 1.0000x reference)
//
#include <hip/hip_runtime.h>

#define N_NODES 100000
#define N_EDGES 600000
#define IN_DIM 128
#define EDGE_DIM 32
#define HIDDEN 128
#define NBLK 391  // ceil(N_NODES/256)

typedef __attribute__((ext_vector_type(8))) short bf16x8;
typedef __attribute__((ext_vector_type(4))) float f32x4;

__device__ inline unsigned short f2bf(float f) {
    unsigned int u = __float_as_uint(f);
    unsigned int r = (u + 0x7FFF + ((u >> 16) & 1)) >> 16;  // RNE
    return (unsigned short)r;
}

// ===========================================================================
// CSR build
// ===========================================================================
__global__ void hist_kernel(const int* __restrict__ dst, int* __restrict__ cnt) {
    int e = blockIdx.x * blockDim.x + threadIdx.x;
    if (e < N_EDGES) atomicAdd(&cnt[dst[e]], 1);
}

__global__ void scan1_kernel(const int* __restrict__ cnt,
                             int* __restrict__ scanout, int* __restrict__ bsum) {
    __shared__ int s[256];
    int tid = threadIdx.x;
    int i = blockIdx.x * 256 + tid;
    int v = (i < N_NODES) ? cnt[i] : 0;
    s[tid] = v;
    __syncthreads();
#pragma unroll
    for (int off = 1; off < 256; off <<= 1) {
        int t = 0;
        if (tid >= off) t = s[tid - off];
        __syncthreads();
        if (tid >= off) s[tid] += t;
        __syncthreads();
    }
    if (i < N_NODES) scanout[i] = s[tid];
    if (tid == 255) bsum[blockIdx.x] = s[255];
}

__global__ void scan2_kernel(int* __restrict__ bsum) {
    __shared__ int s[512];
    int tid = threadIdx.x;
    int v = (tid < NBLK) ? bsum[tid] : 0;
    s[tid] = v;
    __syncthreads();
#pragma unroll
    for (int off = 1; off < 512; off <<= 1) {
        int t = 0;
        if (tid >= off) t = s[tid - off];
        __syncthreads();
        if (tid >= off) s[tid] += t;
        __syncthreads();
    }
    if (tid < NBLK) bsum[tid] = s[tid] - v;  // exclusive
}

__global__ void scan3_kernel(const int* __restrict__ cnt,
                             const int* __restrict__ scanout,
                             const int* __restrict__ bsum,
                             int* __restrict__ rowptr, int* __restrict__ cur) {
    int i = blockIdx.x * 256 + threadIdx.x;
    if (i < N_NODES) {
        int excl = scanout[i] + bsum[i >> 8] - cnt[i];
        rowptr[i] = excl;
        cur[i] = excl;
    }
    if (i == 0) rowptr[N_NODES] = N_EDGES;
}

// pk[pos] = { src | (dst&31)<<27 , edge id } ; psrc[pos] = src | (dst&31)<<27
__global__ void fill_kernel(const int* __restrict__ src, const int* __restrict__ dst,
                            int* __restrict__ cur, int2* __restrict__ pk,
                            int* __restrict__ psrc) {
    int e = blockIdx.x * blockDim.x + threadIdx.x;
    if (e < N_EDGES) {
        int d = dst[e];
        int pos = atomicAdd(&cur[d], 1);
        int packed = src[e] | ((d & 31) << 27);
        int2 v;
        v.x = packed;
        v.y = e;
        pk[pos] = v;
        psrc[pos] = packed;
    }
}

// ===========================================================================
// eam[n][32] = mean of ea rows over incoming edges (graph-invariant, once).
// block = 32 nodes; 256 threads = 8 edges x 32 feats; conflict-free LDS adds.
// ===========================================================================
__global__ __launch_bounds__(256) void eam_kernel(const int* __restrict__ rowptr,
                                                  const int2* __restrict__ pk,
                                                  const float* __restrict__ ea,
                                                  float* __restrict__ eam) {
    __shared__ float s[32][EDGE_DIM];
    __shared__ int s_rp[33];
    int t = threadIdx.x;
    int n0 = blockIdx.x * 32;
    if (t <= 32) s_rp[t] = rowptr[n0 + t];
    for (int i = t; i < 32 * EDGE_DIM; i += 256) ((float*)s)[i] = 0.f;
    __syncthreads();

    int E0 = s_rp[0], E1 = s_rp[32];
    int eg = t >> 5, k = t & 31;
    int pos = E0 + eg;
    for (; pos + 8 < E1; pos += 16) {
        int2 a0 = pk[pos];
        int2 a1 = pk[pos + 8];
        float v0 = ea[a0.y * EDGE_DIM + k];
        float v1 = ea[a1.y * EDGE_DIM + k];
        int ln0 = (unsigned)a0.x >> 27;
        int ln1 = (unsigned)a1.x >> 27;
        atomicAdd(&s[ln0][k], v0);
        atomicAdd(&s[ln1][k], v1);
    }
    if (pos < E1) {
        int2 a0 = pk[pos];
        float v0 = ea[a0.y * EDGE_DIM + k];
        atomicAdd(&s[(unsigned)a0.x >> 27][k], v0);
    }
    __syncthreads();

    for (int i = t; i < 32 * EDGE_DIM; i += 256) {
        int ln = i >> 5;
        int c = s_rp[ln + 1] - s_rp[ln];
        eam[n0 * EDGE_DIM + i] = ((float*)s)[i] / (float)(c > 0 ? c : 1);
    }
}

// ===========================================================================
// WeWl = We @ Wl (32x128), beWl = be @ Wl (128)
// ===========================================================================
__global__ void wewl_kernel(const float* __restrict__ We, const float* __restrict__ be,
                            const float* __restrict__ Wl,
                            float* __restrict__ WeWl, float* __restrict__ beWl) {
    int idx = blockIdx.x * 256 + threadIdx.x;
    if (idx >= 33 * 128) return;
    int r = idx >> 7;
    int n = idx & 127;
    float s = 0.f;
    if (r < 32) {
        for (int j = 0; j < 128; ++j) s += We[r * 128 + j] * Wl[j * 128 + n];
        WeWl[r * 128 + n] = s;
    } else {
        for (int j = 0; j < 128; ++j) s += be[j] * Wl[j * 128 + n];
        beWl[n] = s;
    }
}

// ===========================================================================
// Fused SAGE layer. 16 nodes/block (N_NODES = 16*6250).
// Gather: edge-parallel, lane k handles strided feats {k,k+32,k+64,k+96} so
// every ds_add wave hits banks 0..31 once per half-wave (2-way = free).
// 2 edges/iter, 8 independent x-loads in flight.
// GEMM: K=288 register-tiled fp32, 8 nodes x 1 feat per thread.
// ===========================================================================
__global__ __launch_bounds__(256) void sage_layer_kernel(
        const float* __restrict__ xin,
        const int* __restrict__ rowptr,
        const int* __restrict__ psrc,
        const float* __restrict__ eam,
        const float* __restrict__ WeWl,
        const float* __restrict__ beWl,
        const float* __restrict__ Wl,
        const float* __restrict__ bl,
        const float* __restrict__ Wr,
        const float* __restrict__ br,
        float* __restrict__ out) {
    __shared__ float s_mean[16][HIDDEN];
    __shared__ float s_x[16][HIDDEN];
    __shared__ float s_eam[16][EDGE_DIM];
    __shared__ int s_info[17];

    int t = threadIdx.x;
    int n0 = blockIdx.x * 16;

    if (t <= 16) s_info[t] = rowptr[n0 + t];
    for (int i = t; i < 16 * HIDDEN; i += 256) {
        ((float*)s_mean)[i] = 0.f;
        ((float*)s_x)[i] = xin[n0 * HIDDEN + i];      // contiguous block rows
    }
    for (int i = t; i < 16 * EDGE_DIM; i += 256)
        ((float*)s_eam)[i] = eam[n0 * EDGE_DIM + i];  // precomputed mean(ea)
    __syncthreads();

    // ---- edge-parallel x gather (conflict-free strided features) ----
    int E0 = s_info[0], E1 = s_info[16];
    int eg = t >> 5, k = t & 31;
    int pos = E0 + eg;
    for (; pos + 8 < E1; pos += 16) {
        int a0 = psrc[pos];
        int a1 = psrc[pos + 8];
        int b0 = (a0 & 131071) * HIDDEN;
        int b1 = (a1 & 131071) * HIDDEN;
        float v00 = xin[b0 + k];
        float v01 = xin[b0 + k + 32];
        float v02 = xin[b0 + k + 64];
        float v03 = xin[b0 + k + 96];
        float v10 = xin[b1 + k];
        float v11 = xin[b1 + k + 32];
        float v12 = xin[b1 + k + 64];
        float v13 = xin[b1 + k + 96];
        int ln0 = ((unsigned)a0 >> 27) & 15;
        int ln1 = ((unsigned)a1 >> 27) & 15;
        atomicAdd(&s_mean[ln0][k], v00);
        atomicAdd(&s_mean[ln0][k + 32], v01);
        atomicAdd(&s_mean[ln0][k + 64], v02);
        atomicAdd(&s_mean[ln0][k + 96], v03);
        atomicAdd(&s_mean[ln1][k], v10);
        atomicAdd(&s_mean[ln1][k + 32], v11);
        atomicAdd(&s_mean[ln1][k + 64], v12);
        atomicAdd(&s_mean[ln1][k + 96], v13);
    }
    if (pos < E1) {
        int a0 = psrc[pos];
        int b0 = (a0 & 131071) * HIDDEN;
        float v00 = xin[b0 + k];
        float v01 = xin[b0 + k + 32];
        float v02 = xin[b0 + k + 64];
        float v03 = xin[b0 + k + 96];
        int ln0 = ((unsigned)a0 >> 27) & 15;
        atomicAdd(&s_mean[ln0][k], v00);
        atomicAdd(&s_mean[ln0][k + 32], v01);
        atomicAdd(&s_mean[ln0][k + 64], v02);
        atomicAdd(&s_mean[ln0][k + 96], v03);
    }
    __syncthreads();

    // ---- scale to mean ----
    for (int i = t; i < 16 * HIDDEN; i += 256) {
        int ln = i >> 7;
        int c = s_info[ln + 1] - s_info[ln];
        ((float*)s_mean)[i] /= (float)(c > 0 ? c : 1);
    }
    __syncthreads();

    // ---- GEMM: 8 nodes x 1 feature per thread, K = 128+128+32 ----
    int f = t & 127;
    int g = t >> 7;
    int nb = g * 8;

    float bias = bl[f] + br[f];
    float bw = beWl[f];
    float acc[8];
#pragma unroll
    for (int j = 0; j < 8; ++j) {
        int c = s_info[nb + j + 1] - s_info[nb + j];
        acc[j] = bias + (c > 0 ? bw : 0.f);
    }

    for (int k2 = 0; k2 < HIDDEN; k2 += 4) {
        float wl0 = Wl[(k2 + 0) * HIDDEN + f];
        float wl1 = Wl[(k2 + 1) * HIDDEN + f];
        float wl2 = Wl[(k2 + 2) * HIDDEN + f];
        float wl3 = Wl[(k2 + 3) * HIDDEN + f];
        float wr0 = Wr[(k2 + 0) * HIDDEN + f];
        float wr1 = Wr[(k2 + 1) * HIDDEN + f];
        float wr2 = Wr[(k2 + 2) * HIDDEN + f];
        float wr3 = Wr[(k2 + 3) * HIDDEN + f];
#pragma unroll
        for (int j = 0; j < 8; ++j) {
            float4 m = *(const float4*)&s_mean[nb + j][k2];
            float4 xx = *(const float4*)&s_x[nb + j][k2];
            acc[j] += m.x * wl0 + m.y * wl1 + m.z * wl2 + m.w * wl3
                    + xx.x * wr0 + xx.y * wr1 + xx.z * wr2 + xx.w * wr3;
        }
    }
#pragma unroll
    for (int k2 = 0; k2 < EDGE_DIM; k2 += 4) {
        float w0 = WeWl[(k2 + 0) * HIDDEN + f];
        float w1 = WeWl[(k2 + 1) * HIDDEN + f];
        float w2 = WeWl[(k2 + 2) * HIDDEN + f];
        float w3 = WeWl[(k2 + 3) * HIDDEN + f];
#pragma unroll
        for (int j = 0; j < 8; ++j) {
            float4 e4 = *(const float4*)&s_eam[nb + j][k2];
            acc[j] += e4.x * w0 + e4.y * w1 + e4.z * w2 + e4.w * w3;
        }
    }

#pragma unroll
    for (int j = 0; j < 8; ++j) {
        float v = acc[j];
        out[(n0 + nb + j) * HIDDEN + f] = v > 0.f ? v : 0.f;
    }
}

// ===========================================================================
// Wp1 bf16 fragment swizzle + edge MLP via MFMA (unchanged from R2)
// ===========================================================================
__global__ void wp1_swizzle_kernel(const float* __restrict__ Wp1,
                                   unsigned short* __restrict__ Wp1s) {
    int idx = blockIdx.x * blockDim.x + threadIdx.x;  // 32768 total
    int j = idx & 7;
    int lane = (idx >> 3) & 63;
    int ks = (idx >> 9) & 7;
    int nt = (idx >> 12) & 7;
    int k = ks * 32 + ((lane >> 4) & 3) * 8 + j;
    int n = nt * 16 + (lane & 15);
    Wp1s[idx] = f2bf(Wp1[k * HIDDEN + n]);
}

#define HE_PITCH 264
__global__ __launch_bounds__(256) void edge_mlp_mfma_kernel(
        const float* __restrict__ h,
        const int* __restrict__ src,
        const int* __restrict__ dst,
        const unsigned short* __restrict__ Wp1s,
        const float* __restrict__ bp1,
        const float* __restrict__ Wp2,
        const float* __restrict__ bp2,
        float* __restrict__ out) {
    __shared__ unsigned short s_he[64 * HE_PITCH];

    int t = threadIdx.x;
    int e0 = blockIdx.x * 64;

    int lane32 = t & 31;
    int hr0 = t >> 5;
    for (int hr = hr0; hr < 128; hr += 8) {
        int e = e0 + (hr >> 1);
        int node = (hr & 1) ? dst[e] : src[e];
        float4 v = *(const float4*)&h[node * HIDDEN + lane32 * 4];
        ushort4 w;
        w.x = f2bf(v.x); w.y = f2bf(v.y); w.z = f2bf(v.z); w.w = f2bf(v.w);
        *(ushort4*)&s_he[(hr >> 1) * HE_PITCH + (hr & 1) * 128 + lane32 * 4] = w;
    }
    __syncthreads();

    int wave = t >> 6;
    int lane = t & 63;
    int col = lane & 15;
    int kgrp = lane >> 4;

    f32x4 acc[8];
#pragma unroll
    for (int nt = 0; nt < 8; ++nt) acc[nt] = (f32x4){0.f, 0.f, 0.f, 0.f};

    const bf16x8* __restrict__ Wb = (const bf16x8*)Wp1s;
    const unsigned abase = (wave * 16 + col) * HE_PITCH + kgrp * 8;

#pragma unroll
    for (int ks = 0; ks < 8; ++ks) {
        bf16x8 afrag = *(const bf16x8*)&s_he[abase + ks * 32];
#pragma unroll
        for (int nt = 0; nt < 8; ++nt) {
            bf16x8 bfrag = Wb[(nt * 8 + ks) * 64 + lane];
            acc[nt] = __builtin_amdgcn_mfma_f32_16x16x32_bf16(afrag, bfrag, acc[nt], 0, 0, 0);
        }
    }

    float z[8][4];
#pragma unroll
    for (int nt = 0; nt < 8; ++nt) {
        float b = bp1[nt * 16 + col];
#pragma unroll
        for (int r = 0; r < 4; ++r) {
            float v = acc[nt][r] + b;
            z[nt][r] = v > 0.f ? v : 0.f;
        }
    }

    float w2c0[8], w2c1[8];
#pragma unroll
    for (int nt = 0; nt < 8; ++nt) {
        int n = nt * 16 + col;
        w2c0[nt] = Wp2[n * 2 + 0];
        w2c1[nt] = Wp2[n * 2 + 1];
    }
    float p0[4], p1[4];
#pragma unroll
    for (int r = 0; r < 4; ++r) {
        float a0 = 0.f, a1 = 0.f;
#pragma unroll
        for (int nt = 0; nt < 8; ++nt) {
            a0 += z[nt][r] * w2c0[nt];
            a1 += z[nt][r] * w2c1[nt];
        }
        p0[r] = a0; p1[r] = a1;
    }
#pragma unroll
    for (int m = 8; m >= 1; m >>= 1) {
#pragma unroll
        for (int r = 0; r < 4; ++r) {
            p0[r] += __shfl_xor(p0[r], m);
            p1[r] += __shfl_xor(p1[r], m);
        }
    }
    if (col < 2) {
        float bias = bp2[col];
#pragma unroll
        for (int r = 0; r < 4; ++r) {
            int e = e0 + wave * 16 + kgrp * 4 + r;
            out[e * 2 + col] = (col == 0 ? p0[r] : p1[r]) + bias;
        }
    }
}

// ===========================================================================
extern "C" void kernel_launch(void* const* d_in, const int* in_sizes, int n_in,
                              void* d_out, int out_size, void* d_ws, size_t ws_size,
                              hipStream_t stream) {
    const float* x   = (const float*)d_in[0];
    const int*   ei  = (const int*)d_in[1];
    const float* ea  = (const float*)d_in[2];
    const float* We1 = (const float*)d_in[3];
    const float* be1 = (const float*)d_in[4];
    const float* Wl1 = (const float*)d_in[5];
    const float* bl1 = (const float*)d_in[6];
    const float* Wr1 = (const float*)d_in[7];
    const float* br1 = (const float*)d_in[8];
    const float* We2 = (const float*)d_in[9];
    const float* be2 = (const float*)d_in[10];
    const float* Wl2 = (const float*)d_in[11];
    const float* bl2 = (const float*)d_in[12];
    const float* Wr2 = (const float*)d_in[13];
    const float* br2 = (const float*)d_in[14];
    const float* Wp1 = (const float*)d_in[15];
    const float* bp1 = (const float*)d_in[16];
    const float* Wp2 = (const float*)d_in[17];
    const float* bp2 = (const float*)d_in[18];
    float* out = (float*)d_out;

    const int* src = ei;
    const int* dst = ei + N_EDGES;

    char* ws = (char*)d_ws;
    int*   cnt     = (int*)(ws + 0);
    int*   scanout = (int*)(ws + 409600);
    int*   bsum    = (int*)(ws + 819200);
    int*   rowptr  = (int*)(ws + 827392);
    int*   cur     = (int*)(ws + 1236992);
    int2*  pk      = (int2*)(ws + 1646592);            // 4.8 MB
    int*   psrc    = (int*)(ws + 6446592);             // 2.4 MB
    float* WeWl1   = (float*)(ws + 8846592);
    float* beWl1   = (float*)(ws + 8862976);
    float* WeWl2   = (float*)(ws + 8863488);
    float* beWl2   = (float*)(ws + 8879872);
    float* eam     = (float*)(ws + 8880384);           // 12.8 MB
    float* h1      = (float*)(ws + 21680384);          // 51.2 MB
    float* h2      = (float*)(ws + 72880384);          // 51.2 MB
    unsigned short* Wp1s = (unsigned short*)(ws + 124080384);

    const int EB = (N_EDGES + 255) / 256;

    // ---- CSR build ----
    hipMemsetAsync(cnt, 0, N_NODES * sizeof(int), stream);
    hist_kernel<<<EB, 256, 0, stream>>>(dst, cnt);
    scan1_kernel<<<NBLK, 256, 0, stream>>>(cnt, scanout, bsum);
    scan2_kernel<<<1, 512, 0, stream>>>(bsum);
    scan3_kernel<<<NBLK, 256, 0, stream>>>(cnt, scanout, bsum, rowptr, cur);
    fill_kernel<<<EB, 256, 0, stream>>>(src, dst, cur, pk, psrc);

    // ---- graph-invariant precompute ----
    eam_kernel<<<N_NODES / 32, 256, 0, stream>>>(rowptr, pk, ea, eam);
    wewl_kernel<<<17, 256, 0, stream>>>(We1, be1, Wl1, WeWl1, beWl1);
    wewl_kernel<<<17, 256, 0, stream>>>(We2, be2, Wl2, WeWl2, beWl2);
    wp1_swizzle_kernel<<<32768 / 256, 256, 0, stream>>>(Wp1, Wp1s);

    // ---- layers ----
    sage_layer_kernel<<<N_NODES / 16, 256, 0, stream>>>(
        x, rowptr, psrc, eam, WeWl1, beWl1, Wl1, bl1, Wr1, br1, h1);
    sage_layer_kernel<<<N_NODES / 16, 256, 0, stream>>>(
        h1, rowptr, psrc, eam, WeWl2, beWl2, Wl2, bl2, Wr2, br2, h2);

    // ---- edge predictor (MFMA) ----
    edge_mlp_mfma_kernel<<<N_EDGES / 64, 256, 0, stream>>>(
        h2, src, dst, Wp1s, bp1, Wp2, bp2, out);
}

// Round 6
// 727.780 us; speedup vs baseline: 2.2223x; 2.2223x over previous
//
#include <hip/hip_runtime.h>

#define N_NODES 100000
#define N_EDGES 600000
#define IN_DIM 128
#define EDGE_DIM 32
#define HIDDEN 128
#define NBLK 391  // ceil(N_NODES/256)

typedef __attribute__((ext_vector_type(4))) float f32x4;
typedef _Float16 f16x2 __attribute__((ext_vector_type(2)));
typedef _Float16 f16x8 __attribute__((ext_vector_type(8)));

// ===========================================================================
// CSR build
// ===========================================================================
__global__ void hist_kernel(const int* __restrict__ dst, int* __restrict__ cnt) {
    int e = blockIdx.x * blockDim.x + threadIdx.x;
    if (e < N_EDGES) atomicAdd(&cnt[dst[e]], 1);
}

__global__ void scan1_kernel(const int* __restrict__ cnt,
                             int* __restrict__ scanout, int* __restrict__ bsum) {
    __shared__ int s[256];
    int tid = threadIdx.x;
    int i = blockIdx.x * 256 + tid;
    int v = (i < N_NODES) ? cnt[i] : 0;
    s[tid] = v;
    __syncthreads();
#pragma unroll
    for (int off = 1; off < 256; off <<= 1) {
        int t = 0;
        if (tid >= off) t = s[tid - off];
        __syncthreads();
        if (tid >= off) s[tid] += t;
        __syncthreads();
    }
    if (i < N_NODES) scanout[i] = s[tid];
    if (tid == 255) bsum[blockIdx.x] = s[255];
}

__global__ void scan2_kernel(int* __restrict__ bsum) {
    __shared__ int s[512];
    int tid = threadIdx.x;
    int v = (tid < NBLK) ? bsum[tid] : 0;
    s[tid] = v;
    __syncthreads();
#pragma unroll
    for (int off = 1; off < 512; off <<= 1) {
        int t = 0;
        if (tid >= off) t = s[tid - off];
        __syncthreads();
        if (tid >= off) s[tid] += t;
        __syncthreads();
    }
    if (tid < NBLK) bsum[tid] = s[tid] - v;  // exclusive
}

__global__ void scan3_kernel(const int* __restrict__ cnt,
                             const int* __restrict__ scanout,
                             const int* __restrict__ bsum,
                             int* __restrict__ rowptr, int* __restrict__ cur) {
    int i = blockIdx.x * 256 + threadIdx.x;
    if (i < N_NODES) {
        int excl = scanout[i] + bsum[i >> 8] - cnt[i];
        rowptr[i] = excl;
        cur[i] = excl;
    }
    if (i == 0) rowptr[N_NODES] = N_EDGES;
}

// pk[pos] = { src, edge id }
__global__ void fill_kernel(const int* __restrict__ src, const int* __restrict__ dst,
                            int* __restrict__ cur, int2* __restrict__ pk) {
    int e = blockIdx.x * blockDim.x + threadIdx.x;
    if (e < N_EDGES) {
        int pos = atomicAdd(&cur[dst[e]], 1);
        int2 v;
        v.x = src[e];
        v.y = e;
        pk[pos] = v;
    }
}

// ===========================================================================
// x -> fp16 copy
// ===========================================================================
__global__ void xb_kernel(const float* __restrict__ x, _Float16* __restrict__ xb) {
    int i = blockIdx.x * 256 + threadIdx.x;  // over N*H/2 float2
    if (i < N_NODES * HIDDEN / 2) {
        float2 v = ((const float2*)x)[i];
        f16x2 o;
        o.x = (_Float16)v.x;
        o.y = (_Float16)v.y;
        *(f16x2*)&xb[i * 2] = o;
    }
}

// ===========================================================================
// eamb[n][32] = fp16 mean of ea rows over incoming edges (graph-invariant).
// One wave per 8 nodes; per node: 8 edges/pass, half-wave per edge slot.
// ===========================================================================
__global__ __launch_bounds__(256) void eam_kernel(const int* __restrict__ rowptr,
                                                  const int2* __restrict__ pk,
                                                  const float* __restrict__ ea,
                                                  _Float16* __restrict__ eamb) {
    int wid = blockIdx.x * 4 + (threadIdx.x >> 6);
    int lane = threadIdx.x & 63;
    int half = lane >> 5;
    int k = lane & 31;
    int slot = lane & 7;
    int n0 = wid * 8;
#pragma unroll 1
    for (int j = 0; j < 8; ++j) {
        int n = n0 + j;
        int s = rowptr[n], e = rowptr[n + 1];
        float acc = 0.f;
        int pos = s;
        while (pos < e) {
            int c = e - pos;
            c = c > 8 ? 8 : c;
            int2 pv = pk[pos + (slot < c ? slot : 0)];
            float r[4];
#pragma unroll
            for (int u = 0; u < 4; ++u) {
                int uu = half + 2 * u;
                if (uu < c) {
                    int eid = __shfl(pv.y, uu);
                    r[u] = ea[eid * EDGE_DIM + k];
                }
            }
#pragma unroll
            for (int u = 0; u < 4; ++u) {
                int uu = half + 2 * u;
                if (uu < c) acc += r[u];
            }
            pos += c;
        }
        acc += __shfl_xor(acc, 32);
        float d = (float)(e - s);
        d = d > 1.f ? d : 1.f;
        if (lane < 32) eamb[n * EDGE_DIM + k] = (_Float16)(acc / d);
    }
}

// ===========================================================================
// WeWl = We @ Wl (32x128) fp32, beWl = be @ Wl (128) fp32
// ===========================================================================
__global__ void wewl_kernel(const float* __restrict__ We, const float* __restrict__ be,
                            const float* __restrict__ Wl,
                            float* __restrict__ WeWl, float* __restrict__ beWl) {
    int idx = blockIdx.x * 256 + threadIdx.x;
    if (idx >= 33 * 128) return;
    int r = idx >> 7;
    int n = idx & 127;
    float s = 0.f;
    if (r < 32) {
        for (int j = 0; j < 128; ++j) s += We[r * 128 + j] * Wl[j * 128 + n];
        WeWl[r * 128 + n] = s;
    } else {
        for (int j = 0; j < 128; ++j) s += be[j] * Wl[j * 128 + n];
        beWl[n] = s;
    }
}

// ===========================================================================
// Wbig = [Wl(128); Wr(128); WeWl(32)] -> fp16 MFMA B-fragment order, K=288.
// idx = ((nt*9 + ks)*64 + lane)*8 + j ; k = ks*32+((lane>>4)&3)*8+j ; n = nt*16+(lane&15)
// ===========================================================================
__global__ void wbig_swizzle_kernel(const float* __restrict__ Wl,
                                    const float* __restrict__ Wr,
                                    const float* __restrict__ WeWl,
                                    _Float16* __restrict__ Wbs) {
    int idx = blockIdx.x * 256 + threadIdx.x;
    if (idx >= 8 * 9 * 64 * 8) return;  // 36864
    int j = idx & 7;
    int lane = (idx >> 3) & 63;
    int rem = idx >> 9;  // 0..71
    int ks = rem % 9;
    int nt = rem / 9;
    int k = ks * 32 + ((lane >> 4) & 3) * 8 + j;
    int n = nt * 16 + (lane & 15);
    float v = (k < 128) ? Wl[k * 128 + n]
            : (k < 256) ? Wr[(k - 128) * 128 + n]
                        : WeWl[(k - 256) * 128 + n];
    Wbs[idx] = (_Float16)v;
}

// ===========================================================================
// Per-wave VGPR aggregation: meanb[n] = fp16( mean over in-edges of xin[src] ).
// One wave handles 8 nodes (4 pairs). Per pass: 16 independent 256B row loads
// in flight (8 per node), indices fetched lane-parallel + shfl-broadcast.
// ===========================================================================
__global__ __launch_bounds__(256) void agg_kernel(const _Float16* __restrict__ xin,
                                                  const int* __restrict__ rowptr,
                                                  const int2* __restrict__ pk,
                                                  _Float16* __restrict__ meanb) {
    int wid = blockIdx.x * 4 + (threadIdx.x >> 6);
    int lane = threadIdx.x & 63;
    int slot = lane & 7;
    int n0 = wid * 8;
#pragma unroll 1
    for (int pr = 0; pr < 4; ++pr) {
        int nA = n0 + pr * 2;
        int sA = rowptr[nA];
        int sB = rowptr[nA + 1];
        int eB = rowptr[nA + 2];
        float aAx = 0.f, aAy = 0.f, aBx = 0.f, aBy = 0.f;
        int pA = sA, pB = sB;
        while (pA < sB || pB < eB) {
            int cA = sB - pA; cA = cA > 8 ? 8 : cA;
            int cB = eB - pB; cB = cB > 8 ? 8 : cB;
            int base = (lane & 8) ? pB : pA;
            int lim  = (lane & 8) ? cB : cA;
            int2 pv = pk[base + (slot < lim ? slot : 0)];
            f16x2 rA[8], rB[8];
#pragma unroll
            for (int u = 0; u < 8; ++u)
                if (u < cA) {
                    int s = __shfl(pv.x, u);
                    rA[u] = *(const f16x2*)&xin[s * HIDDEN + lane * 2];
                }
#pragma unroll
            for (int u = 0; u < 8; ++u)
                if (u < cB) {
                    int s = __shfl(pv.x, 8 + u);
                    rB[u] = *(const f16x2*)&xin[s * HIDDEN + lane * 2];
                }
#pragma unroll
            for (int u = 0; u < 8; ++u)
                if (u < cA) { aAx += (float)rA[u].x; aAy += (float)rA[u].y; }
#pragma unroll
            for (int u = 0; u < 8; ++u)
                if (u < cB) { aBx += (float)rB[u].x; aBy += (float)rB[u].y; }
            pA += cA;
            pB += cB;
        }
        float dA = (float)(sB - sA); dA = dA > 1.f ? dA : 1.f;
        float dB = (float)(eB - sB); dB = dB > 1.f ? dB : 1.f;
        f16x2 oA, oB;
        oA.x = (_Float16)(aAx / dA); oA.y = (_Float16)(aAy / dA);
        oB.x = (_Float16)(aBx / dB); oB.y = (_Float16)(aBy / dB);
        *(f16x2*)&meanb[nA * HIDDEN + lane * 2] = oA;
        *(f16x2*)&meanb[(nA + 1) * HIDDEN + lane * 2] = oB;
    }
}

// ===========================================================================
// Node GEMM via f16 MFMA: out = relu([mean|x|eam] @ [Wl;Wr;WeWl] + bias), K=288.
// 64 nodes/block, 4 waves x 16 nodes, 9 k-steps of 16x16x32.
// ===========================================================================
#define APITCH 296  // 288 + 8 f16 pad
__global__ __launch_bounds__(256) void node_gemm_kernel(
        const _Float16* __restrict__ meanb,
        const _Float16* __restrict__ xb,
        const _Float16* __restrict__ eamb,
        const _Float16* __restrict__ Wbs,
        const int* __restrict__ rowptr,
        const float* __restrict__ bl, const float* __restrict__ br,
        const float* __restrict__ beWl,
        _Float16* __restrict__ outb) {
    __shared__ _Float16 s_a[64 * APITCH];  // 37888 B
    __shared__ float s_bias[128];
    __shared__ float s_bw[128];
    __shared__ int s_deg[64];
    int t = threadIdx.x;
    int n0 = blockIdx.x * 64;

    if (t < 128) {
        s_bias[t] = bl[t] + br[t];
        s_bw[t] = beWl[t];
    } else if (t < 192) {
        int m = t - 128;
        int n = n0 + m;
        n = n < N_NODES ? n : N_NODES - 1;
        s_deg[m] = rowptr[n + 1] - rowptr[n];
    }
    for (int i = t; i < 64 * 16; i += 256) {
        int row = i >> 4, seg = i & 15;
        int n = n0 + row;
        n = n < N_NODES ? n : N_NODES - 1;
        *(f16x8*)&s_a[row * APITCH + seg * 8] = *(const f16x8*)&meanb[n * HIDDEN + seg * 8];
        *(f16x8*)&s_a[row * APITCH + 128 + seg * 8] = *(const f16x8*)&xb[n * HIDDEN + seg * 8];
    }
    for (int i = t; i < 64 * 4; i += 256) {
        int row = i >> 2, seg = i & 3;
        int n = n0 + row;
        n = n < N_NODES ? n : N_NODES - 1;
        *(f16x8*)&s_a[row * APITCH + 256 + seg * 8] = *(const f16x8*)&eamb[n * EDGE_DIM + seg * 8];
    }
    __syncthreads();

    int wave = t >> 6;
    int lane = t & 63;
    int col = lane & 15;
    int kgrp = lane >> 4;

    f32x4 acc[8];
#pragma unroll
    for (int nt = 0; nt < 8; ++nt) acc[nt] = (f32x4){0.f, 0.f, 0.f, 0.f};

    const f16x8* __restrict__ Wb = (const f16x8*)Wbs;
#pragma unroll
    for (int ks = 0; ks < 9; ++ks) {
        f16x8 afrag = *(const f16x8*)&s_a[(wave * 16 + col) * APITCH + ks * 32 + kgrp * 8];
#pragma unroll
        for (int nt = 0; nt < 8; ++nt) {
            f16x8 bfrag = Wb[(nt * 9 + ks) * 64 + lane];
            acc[nt] = __builtin_amdgcn_mfma_f32_16x16x32_f16(afrag, bfrag, acc[nt], 0, 0, 0);
        }
    }

#pragma unroll
    for (int nt = 0; nt < 8; ++nt) {
        int feat = nt * 16 + col;
        float b = s_bias[feat];
        float bw = s_bw[feat];
#pragma unroll
        for (int r = 0; r < 4; ++r) {
            int m = wave * 16 + kgrp * 4 + r;
            int n = n0 + m;
            float v = acc[nt][r] + b + (s_deg[m] > 0 ? bw : 0.f);
            v = v > 0.f ? v : 0.f;
            if (n < N_NODES) outb[n * HIDDEN + feat] = (_Float16)v;
        }
    }
}

// ===========================================================================
// Wp1 fp16 fragment swizzle (layout as R2, dtype now f16)
// ===========================================================================
__global__ void wp1_swizzle_kernel(const float* __restrict__ Wp1,
                                   _Float16* __restrict__ Wp1s) {
    int idx = blockIdx.x * blockDim.x + threadIdx.x;  // 32768 total
    int j = idx & 7;
    int lane = (idx >> 3) & 63;
    int ks = (idx >> 9) & 7;
    int nt = (idx >> 12) & 7;
    int k = ks * 32 + ((lane >> 4) & 3) * 8 + j;
    int n = nt * 16 + (lane & 15);
    Wp1s[idx] = (_Float16)Wp1[k * HIDDEN + n];
}

// ===========================================================================
// Edge MLP via f16 MFMA; h input already fp16 (raw ushort copy to LDS).
// ===========================================================================
#define HE_PITCH 264
__global__ __launch_bounds__(256) void edge_mlp_mfma_kernel(
        const unsigned short* __restrict__ h,   // fp16 bits
        const int* __restrict__ src,
        const int* __restrict__ dst,
        const _Float16* __restrict__ Wp1s,
        const float* __restrict__ bp1,
        const float* __restrict__ Wp2,
        const float* __restrict__ bp2,
        float* __restrict__ out) {
    __shared__ unsigned short s_he[64 * HE_PITCH];

    int t = threadIdx.x;
    int e0 = blockIdx.x * 64;  // N_EDGES = 64*9375 exactly

    int lane32 = t & 31;
    int hr0 = t >> 5;
    for (int hr = hr0; hr < 128; hr += 8) {
        int e = e0 + (hr >> 1);
        int node = (hr & 1) ? dst[e] : src[e];
        *(ushort4*)&s_he[(hr >> 1) * HE_PITCH + (hr & 1) * 128 + lane32 * 4] =
            *(const ushort4*)&h[node * HIDDEN + lane32 * 4];
    }
    __syncthreads();

    int wave = t >> 6;
    int lane = t & 63;
    int col = lane & 15;
    int kgrp = lane >> 4;

    f32x4 acc[8];
#pragma unroll
    for (int nt = 0; nt < 8; ++nt) acc[nt] = (f32x4){0.f, 0.f, 0.f, 0.f};

    const f16x8* __restrict__ Wb = (const f16x8*)Wp1s;
    const unsigned abase = (wave * 16 + col) * HE_PITCH + kgrp * 8;

#pragma unroll
    for (int ks = 0; ks < 8; ++ks) {
        f16x8 afrag = *(const f16x8*)&s_he[abase + ks * 32];
#pragma unroll
        for (int nt = 0; nt < 8; ++nt) {
            f16x8 bfrag = Wb[(nt * 8 + ks) * 64 + lane];
            acc[nt] = __builtin_amdgcn_mfma_f32_16x16x32_f16(afrag, bfrag, acc[nt], 0, 0, 0);
        }
    }

    float z[8][4];
#pragma unroll
    for (int nt = 0; nt < 8; ++nt) {
        float b = bp1[nt * 16 + col];
#pragma unroll
        for (int r = 0; r < 4; ++r) {
            float v = acc[nt][r] + b;
            z[nt][r] = v > 0.f ? v : 0.f;
        }
    }

    float w2c0[8], w2c1[8];
#pragma unroll
    for (int nt = 0; nt < 8; ++nt) {
        int n = nt * 16 + col;
        w2c0[nt] = Wp2[n * 2 + 0];
        w2c1[nt] = Wp2[n * 2 + 1];
    }
    float p0[4], p1[4];
#pragma unroll
    for (int r = 0; r < 4; ++r) {
        float a0 = 0.f, a1 = 0.f;
#pragma unroll
        for (int nt = 0; nt < 8; ++nt) {
            a0 += z[nt][r] * w2c0[nt];
            a1 += z[nt][r] * w2c1[nt];
        }
        p0[r] = a0; p1[r] = a1;
    }
#pragma unroll
    for (int m = 8; m >= 1; m >>= 1) {
#pragma unroll
        for (int r = 0; r < 4; ++r) {
            p0[r] += __shfl_xor(p0[r], m);
            p1[r] += __shfl_xor(p1[r], m);
        }
    }
    if (col < 2) {
        float bias = bp2[col];
#pragma unroll
        for (int r = 0; r < 4; ++r) {
            int e = e0 + wave * 16 + kgrp * 4 + r;
            out[e * 2 + col] = (col == 0 ? p0[r] : p1[r]) + bias;
        }
    }
}

// ===========================================================================
extern "C" void kernel_launch(void* const* d_in, const int* in_sizes, int n_in,
                              void* d_out, int out_size, void* d_ws, size_t ws_size,
                              hipStream_t stream) {
    const float* x   = (const float*)d_in[0];
    const int*   ei  = (const int*)d_in[1];
    const float* ea  = (const float*)d_in[2];
    const float* We1 = (const float*)d_in[3];
    const float* be1 = (const float*)d_in[4];
    const float* Wl1 = (const float*)d_in[5];
    const float* bl1 = (const float*)d_in[6];
    const float* Wr1 = (const float*)d_in[7];
    const float* br1 = (const float*)d_in[8];
    const float* We2 = (const float*)d_in[9];
    const float* be2 = (const float*)d_in[10];
    const float* Wl2 = (const float*)d_in[11];
    const float* bl2 = (const float*)d_in[12];
    const float* Wr2 = (const float*)d_in[13];
    const float* br2 = (const float*)d_in[14];
    const float* Wp1 = (const float*)d_in[15];
    const float* bp1 = (const float*)d_in[16];
    const float* Wp2 = (const float*)d_in[17];
    const float* bp2 = (const float*)d_in[18];
    float* out = (float*)d_out;

    const int* src = ei;
    const int* dst = ei + N_EDGES;

    char* ws = (char*)d_ws;
    int*   cnt     = (int*)(ws + 0);           // 409600
    int*   scanout = (int*)(ws + 409600);      // 409600
    int*   bsum    = (int*)(ws + 819200);      // 8192
    int*   rowptr  = (int*)(ws + 827392);      // 409600 (N+1 ints)
    int*   cur     = (int*)(ws + 1236992);     // 409600
    int2*  pk      = (int2*)(ws + 1646592);    // (600000+8)*8 -> 4800512
    float* WeWl1   = (float*)(ws + 6447104);   // 16384
    float* beWl1   = (float*)(ws + 6463488);   // 512
    float* WeWl2   = (float*)(ws + 6464000);   // 16384
    float* beWl2   = (float*)(ws + 6480384);   // 512
    _Float16* eamb = (_Float16*)(ws + 6480896);   // 6.4 MB
    _Float16* xb   = (_Float16*)(ws + 12880896);  // 25.6 MB
    _Float16* meanb= (_Float16*)(ws + 38480896);  // 25.6 MB (reused both layers)
    _Float16* h1b  = (_Float16*)(ws + 64080896);  // 25.6 MB
    _Float16* h2b  = (_Float16*)(ws + 89680896);  // 25.6 MB
    _Float16* Wbs1 = (_Float16*)(ws + 115280896); // 73728
    _Float16* Wbs2 = (_Float16*)(ws + 115354624); // 73728
    _Float16* Wp1s = (_Float16*)(ws + 115428352); // 65536

    const int EB = (N_EDGES + 255) / 256;

    // ---- CSR build ----
    hipMemsetAsync(cnt, 0, N_NODES * sizeof(int), stream);
    hist_kernel<<<EB, 256, 0, stream>>>(dst, cnt);
    scan1_kernel<<<NBLK, 256, 0, stream>>>(cnt, scanout, bsum);
    scan2_kernel<<<1, 512, 0, stream>>>(bsum);
    scan3_kernel<<<NBLK, 256, 0, stream>>>(cnt, scanout, bsum, rowptr, cur);
    fill_kernel<<<EB, 256, 0, stream>>>(src, dst, cur, pk);

    // ---- graph-invariant precompute ----
    eam_kernel<<<N_NODES / 32, 256, 0, stream>>>(rowptr, pk, ea, eamb);
    wewl_kernel<<<17, 256, 0, stream>>>(We1, be1, Wl1, WeWl1, beWl1);
    wewl_kernel<<<17, 256, 0, stream>>>(We2, be2, Wl2, WeWl2, beWl2);
    xb_kernel<<<(N_NODES * HIDDEN / 2 + 255) / 256, 256, 0, stream>>>(x, xb);
    wbig_swizzle_kernel<<<144, 256, 0, stream>>>(Wl1, Wr1, WeWl1, Wbs1);
    wbig_swizzle_kernel<<<144, 256, 0, stream>>>(Wl2, Wr2, WeWl2, Wbs2);
    wp1_swizzle_kernel<<<128, 256, 0, stream>>>(Wp1, Wp1s);

    // ---- layer 1 ----
    agg_kernel<<<N_NODES / 32, 256, 0, stream>>>(xb, rowptr, pk, meanb);
    node_gemm_kernel<<<(N_NODES + 63) / 64, 256, 0, stream>>>(
        meanb, xb, eamb, Wbs1, rowptr, bl1, br1, beWl1, h1b);

    // ---- layer 2 ----
    agg_kernel<<<N_NODES / 32, 256, 0, stream>>>(h1b, rowptr, pk, meanb);
    node_gemm_kernel<<<(N_NODES + 63) / 64, 256, 0, stream>>>(
        meanb, h1b, eamb, Wbs2, rowptr, bl2, br2, beWl2, h2b);

    // ---- edge predictor ----
    edge_mlp_mfma_kernel<<<N_EDGES / 64, 256, 0, stream>>>(
        (const unsigned short*)h2b, src, dst, Wp1s, bp1, Wp2, bp2, out);
}

// Round 7
// 566.853 us; speedup vs baseline: 2.8532x; 1.2839x over previous
//
#include <hip/hip_runtime.h>

#define N_NODES 100000
#define N_EDGES 600000
#define IN_DIM 128
#define EDGE_DIM 32
#define HIDDEN 128
#define NBLK 391  // ceil(N_NODES/256)

typedef __attribute__((ext_vector_type(4))) float f32x4;
typedef _Float16 f16x2 __attribute__((ext_vector_type(2)));
typedef _Float16 f16x4 __attribute__((ext_vector_type(4)));
typedef _Float16 f16x8 __attribute__((ext_vector_type(8)));

// ===========================================================================
// CSR build
// ===========================================================================
__global__ void hist_kernel(const int* __restrict__ dst, int* __restrict__ cnt) {
    int e = blockIdx.x * blockDim.x + threadIdx.x;
    if (e < N_EDGES) atomicAdd(&cnt[dst[e]], 1);
}

__global__ void scan1_kernel(const int* __restrict__ cnt,
                             int* __restrict__ scanout, int* __restrict__ bsum) {
    __shared__ int s[256];
    int tid = threadIdx.x;
    int i = blockIdx.x * 256 + tid;
    int v = (i < N_NODES) ? cnt[i] : 0;
    s[tid] = v;
    __syncthreads();
#pragma unroll
    for (int off = 1; off < 256; off <<= 1) {
        int t = 0;
        if (tid >= off) t = s[tid - off];
        __syncthreads();
        if (tid >= off) s[tid] += t;
        __syncthreads();
    }
    if (i < N_NODES) scanout[i] = s[tid];
    if (tid == 255) bsum[blockIdx.x] = s[255];
}

__global__ void scan2_kernel(int* __restrict__ bsum) {
    __shared__ int s[512];
    int tid = threadIdx.x;
    int v = (tid < NBLK) ? bsum[tid] : 0;
    s[tid] = v;
    __syncthreads();
#pragma unroll
    for (int off = 1; off < 512; off <<= 1) {
        int t = 0;
        if (tid >= off) t = s[tid - off];
        __syncthreads();
        if (tid >= off) s[tid] += t;
        __syncthreads();
    }
    if (tid < NBLK) bsum[tid] = s[tid] - v;  // exclusive
}

__global__ void scan3_kernel(const int* __restrict__ cnt,
                             const int* __restrict__ scanout,
                             const int* __restrict__ bsum,
                             int* __restrict__ rowptr, int* __restrict__ cur) {
    int i = blockIdx.x * 256 + threadIdx.x;
    if (i < N_NODES) {
        int excl = scanout[i] + bsum[i >> 8] - cnt[i];
        rowptr[i] = excl;
        cur[i] = excl;
    }
    if (i == 0) rowptr[N_NODES] = N_EDGES;
}

// pk[pos] = { src, edge id } ; pdst[pos] = dst
__global__ void fill_kernel(const int* __restrict__ src, const int* __restrict__ dst,
                            int* __restrict__ cur, int2* __restrict__ pk,
                            int* __restrict__ pdst) {
    int e = blockIdx.x * blockDim.x + threadIdx.x;
    if (e < N_EDGES) {
        int d = dst[e];
        int pos = atomicAdd(&cur[d], 1);
        int2 v;
        v.x = src[e];
        v.y = e;
        pk[pos] = v;
        pdst[pos] = d;
    }
}

// ===========================================================================
// x -> fp16 copy
// ===========================================================================
__global__ void xb_kernel(const float* __restrict__ x, _Float16* __restrict__ xb) {
    int i = blockIdx.x * 256 + threadIdx.x;  // over N*H/2 float2
    if (i < N_NODES * HIDDEN / 2) {
        float2 v = ((const float2*)x)[i];
        f16x2 o;
        o.x = (_Float16)v.x;
        o.y = (_Float16)v.y;
        *(f16x2*)&xb[i * 2] = o;
    }
}

// ===========================================================================
// eamb[n][32] = fp16 mean of ea rows over incoming edges (graph-invariant).
// ===========================================================================
__global__ __launch_bounds__(256) void eam_kernel(const int* __restrict__ rowptr,
                                                  const int2* __restrict__ pk,
                                                  const float* __restrict__ ea,
                                                  _Float16* __restrict__ eamb) {
    int wid = blockIdx.x * 4 + (threadIdx.x >> 6);
    int lane = threadIdx.x & 63;
    int half = lane >> 5;
    int k = lane & 31;
    int slot = lane & 7;
    int n0 = wid * 8;
#pragma unroll 1
    for (int j = 0; j < 8; ++j) {
        int n = n0 + j;
        int s = rowptr[n], e = rowptr[n + 1];
        float acc = 0.f;
        int pos = s;
        while (pos < e) {
            int c = e - pos;
            c = c > 8 ? 8 : c;
            int2 pv = pk[pos + (slot < c ? slot : 0)];
            float r[4];
#pragma unroll
            for (int u = 0; u < 4; ++u) {
                int uu = half + 2 * u;
                if (uu < c) {
                    int eid = __shfl(pv.y, uu);
                    r[u] = ea[eid * EDGE_DIM + k];
                }
            }
#pragma unroll
            for (int u = 0; u < 4; ++u) {
                int uu = half + 2 * u;
                if (uu < c) acc += r[u];
            }
            pos += c;
        }
        acc += __shfl_xor(acc, 32);
        float d = (float)(e - s);
        d = d > 1.f ? d : 1.f;
        if (lane < 32) eamb[n * EDGE_DIM + k] = (_Float16)(acc / d);
    }
}

// ===========================================================================
// WeWl = We @ Wl (32x128) fp32, beWl = be @ Wl (128) fp32
// ===========================================================================
__global__ void wewl_kernel(const float* __restrict__ We, const float* __restrict__ be,
                            const float* __restrict__ Wl,
                            float* __restrict__ WeWl, float* __restrict__ beWl) {
    int idx = blockIdx.x * 256 + threadIdx.x;
    if (idx >= 33 * 128) return;
    int r = idx >> 7;
    int n = idx & 127;
    float s = 0.f;
    if (r < 32) {
        for (int j = 0; j < 128; ++j) s += We[r * 128 + j] * Wl[j * 128 + n];
        WeWl[r * 128 + n] = s;
    } else {
        for (int j = 0; j < 128; ++j) s += be[j] * Wl[j * 128 + n];
        beWl[n] = s;
    }
}

// ===========================================================================
// Wbig = [Wl(128); Wr(128); WeWl(32)] -> fp16 MFMA B-fragment order, K=288.
// ===========================================================================
__global__ void wbig_swizzle_kernel(const float* __restrict__ Wl,
                                    const float* __restrict__ Wr,
                                    const float* __restrict__ WeWl,
                                    _Float16* __restrict__ Wbs) {
    int idx = blockIdx.x * 256 + threadIdx.x;
    if (idx >= 8 * 9 * 64 * 8) return;  // 36864
    int j = idx & 7;
    int lane = (idx >> 3) & 63;
    int rem = idx >> 9;  // 0..71
    int ks = rem % 9;
    int nt = rem / 9;
    int k = ks * 32 + ((lane >> 4) & 3) * 8 + j;
    int n = nt * 16 + (lane & 15);
    float v = (k < 128) ? Wl[k * 128 + n]
            : (k < 256) ? Wr[(k - 128) * 128 + n]
                        : WeWl[(k - 256) * 128 + n];
    Wbs[idx] = (_Float16)v;
}

// ===========================================================================
// Per-wave VGPR aggregation: meanb[n] = fp16( mean over in-edges of xin[src] ).
// ===========================================================================
__global__ __launch_bounds__(256) void agg_kernel(const _Float16* __restrict__ xin,
                                                  const int* __restrict__ rowptr,
                                                  const int2* __restrict__ pk,
                                                  _Float16* __restrict__ meanb) {
    int wid = blockIdx.x * 4 + (threadIdx.x >> 6);
    int lane = threadIdx.x & 63;
    int slot = lane & 7;
    int n0 = wid * 8;
#pragma unroll 1
    for (int pr = 0; pr < 4; ++pr) {
        int nA = n0 + pr * 2;
        int sA = rowptr[nA];
        int sB = rowptr[nA + 1];
        int eB = rowptr[nA + 2];
        float aAx = 0.f, aAy = 0.f, aBx = 0.f, aBy = 0.f;
        int pA = sA, pB = sB;
        while (pA < sB || pB < eB) {
            int cA = sB - pA; cA = cA > 8 ? 8 : cA;
            int cB = eB - pB; cB = cB > 8 ? 8 : cB;
            int base = (lane & 8) ? pB : pA;
            int lim  = (lane & 8) ? cB : cA;
            int2 pv = pk[base + (slot < lim ? slot : 0)];
            f16x2 rA[8], rB[8];
#pragma unroll
            for (int u = 0; u < 8; ++u)
                if (u < cA) {
                    int s = __shfl(pv.x, u);
                    rA[u] = *(const f16x2*)&xin[s * HIDDEN + lane * 2];
                }
#pragma unroll
            for (int u = 0; u < 8; ++u)
                if (u < cB) {
                    int s = __shfl(pv.x, 8 + u);
                    rB[u] = *(const f16x2*)&xin[s * HIDDEN + lane * 2];
                }
#pragma unroll
            for (int u = 0; u < 8; ++u)
                if (u < cA) { aAx += (float)rA[u].x; aAy += (float)rA[u].y; }
#pragma unroll
            for (int u = 0; u < 8; ++u)
                if (u < cB) { aBx += (float)rB[u].x; aBy += (float)rB[u].y; }
            pA += cA;
            pB += cB;
        }
        float dA = (float)(sB - sA); dA = dA > 1.f ? dA : 1.f;
        float dB = (float)(eB - sB); dB = dB > 1.f ? dB : 1.f;
        f16x2 oA, oB;
        oA.x = (_Float16)(aAx / dA); oA.y = (_Float16)(aAy / dA);
        oB.x = (_Float16)(aBx / dB); oB.y = (_Float16)(aBy / dB);
        *(f16x2*)&meanb[nA * HIDDEN + lane * 2] = oA;
        *(f16x2*)&meanb[(nA + 1) * HIDDEN + lane * 2] = oB;
    }
}

// ===========================================================================
// Node GEMM via f16 MFMA: out = relu([mean|x|eam] @ [Wl;Wr;WeWl] + bias), K=288.
// ===========================================================================
#define APITCH 296  // 288 + 8 f16 pad
__global__ __launch_bounds__(256) void node_gemm_kernel(
        const _Float16* __restrict__ meanb,
        const _Float16* __restrict__ xb,
        const _Float16* __restrict__ eamb,
        const _Float16* __restrict__ Wbs,
        const int* __restrict__ rowptr,
        const float* __restrict__ bl, const float* __restrict__ br,
        const float* __restrict__ beWl,
        _Float16* __restrict__ outb) {
    __shared__ _Float16 s_a[64 * APITCH];  // 37888 B
    __shared__ float s_bias[128];
    __shared__ float s_bw[128];
    __shared__ int s_deg[64];
    int t = threadIdx.x;
    int n0 = blockIdx.x * 64;

    if (t < 128) {
        s_bias[t] = bl[t] + br[t];
        s_bw[t] = beWl[t];
    } else if (t < 192) {
        int m = t - 128;
        int n = n0 + m;
        n = n < N_NODES ? n : N_NODES - 1;
        s_deg[m] = rowptr[n + 1] - rowptr[n];
    }
    for (int i = t; i < 64 * 16; i += 256) {
        int row = i >> 4, seg = i & 15;
        int n = n0 + row;
        n = n < N_NODES ? n : N_NODES - 1;
        *(f16x8*)&s_a[row * APITCH + seg * 8] = *(const f16x8*)&meanb[n * HIDDEN + seg * 8];
        *(f16x8*)&s_a[row * APITCH + 128 + seg * 8] = *(const f16x8*)&xb[n * HIDDEN + seg * 8];
    }
    for (int i = t; i < 64 * 4; i += 256) {
        int row = i >> 2, seg = i & 3;
        int n = n0 + row;
        n = n < N_NODES ? n : N_NODES - 1;
        *(f16x8*)&s_a[row * APITCH + 256 + seg * 8] = *(const f16x8*)&eamb[n * EDGE_DIM + seg * 8];
    }
    __syncthreads();

    int wave = t >> 6;
    int lane = t & 63;
    int col = lane & 15;
    int kgrp = lane >> 4;

    f32x4 acc[8];
#pragma unroll
    for (int nt = 0; nt < 8; ++nt) acc[nt] = (f32x4){0.f, 0.f, 0.f, 0.f};

    const f16x8* __restrict__ Wb = (const f16x8*)Wbs;
#pragma unroll
    for (int ks = 0; ks < 9; ++ks) {
        f16x8 afrag = *(const f16x8*)&s_a[(wave * 16 + col) * APITCH + ks * 32 + kgrp * 8];
#pragma unroll
        for (int nt = 0; nt < 8; ++nt) {
            f16x8 bfrag = Wb[(nt * 9 + ks) * 64 + lane];
            acc[nt] = __builtin_amdgcn_mfma_f32_16x16x32_f16(afrag, bfrag, acc[nt], 0, 0, 0);
        }
    }

#pragma unroll
    for (int nt = 0; nt < 8; ++nt) {
        int feat = nt * 16 + col;
        float b = s_bias[feat];
        float bw = s_bw[feat];
#pragma unroll
        for (int r = 0; r < 4; ++r) {
            int m = wave * 16 + kgrp * 4 + r;
            int n = n0 + m;
            float v = acc[nt][r] + b + (s_deg[m] > 0 ? bw : 0.f);
            v = v > 0.f ? v : 0.f;
            if (n < N_NODES) outb[n * HIDDEN + feat] = (_Float16)v;
        }
    }
}

// ===========================================================================
// Wp1 -> UV-GEMM B fragments: K=128 (h dims), N=256 (U cols | V cols).
// idx = ((nt*4+ks)*64+lane)*8+j ; k = ks*32+((lane>>4)&3)*8+j ; n = nt*16+(lane&15)
// n<128: U col (Wp1[k][n]) ; n>=128: V col (Wp1[128+k][n-128])
// ===========================================================================
__global__ void wp1uv_swizzle_kernel(const float* __restrict__ Wp1,
                                     _Float16* __restrict__ Wuv) {
    int idx = blockIdx.x * 256 + threadIdx.x;  // 32768
    if (idx >= 32768) return;
    int j = idx & 7;
    int lane = (idx >> 3) & 63;
    int ks = (idx >> 9) & 3;
    int nt = (idx >> 11) & 15;
    int k = ks * 32 + ((lane >> 4) & 3) * 8 + j;
    int n = nt * 16 + (lane & 15);
    float v = (n < 128) ? Wp1[k * 128 + n] : Wp1[(128 + k) * 128 + (n - 128)];
    Wuv[idx] = (_Float16)v;
}

// ===========================================================================
// UV GEMM: UV[n][0:128] = h[n]@Wp1_top + bp1 ; UV[n][128:256] = h[n]@Wp1_bot.
// 64 nodes/block, K=128 (4 ksteps), N=256 (16 n-tiles). No relu.
// ===========================================================================
#define UPITCH 136  // 128 + 8 f16 pad
__global__ __launch_bounds__(256) void uv_gemm_kernel(
        const _Float16* __restrict__ h,
        const _Float16* __restrict__ Wuv,
        const float* __restrict__ bp1,
        _Float16* __restrict__ UV) {
    __shared__ _Float16 s_a[64 * UPITCH];  // 17408 B
    __shared__ float s_bias[256];
    int t = threadIdx.x;
    int n0 = blockIdx.x * 64;

    s_bias[t] = (t < 128) ? bp1[t] : 0.f;
    for (int i = t; i < 64 * 16; i += 256) {
        int row = i >> 4, seg = i & 15;
        int n = n0 + row;
        n = n < N_NODES ? n : N_NODES - 1;
        *(f16x8*)&s_a[row * UPITCH + seg * 8] = *(const f16x8*)&h[n * HIDDEN + seg * 8];
    }
    __syncthreads();

    int wave = t >> 6;
    int lane = t & 63;
    int col = lane & 15;
    int kgrp = lane >> 4;

    f32x4 acc[16];
#pragma unroll
    for (int nt = 0; nt < 16; ++nt) acc[nt] = (f32x4){0.f, 0.f, 0.f, 0.f};

    const f16x8* __restrict__ Wb = (const f16x8*)Wuv;
#pragma unroll
    for (int ks = 0; ks < 4; ++ks) {
        f16x8 afrag = *(const f16x8*)&s_a[(wave * 16 + col) * UPITCH + ks * 32 + kgrp * 8];
#pragma unroll
        for (int nt = 0; nt < 16; ++nt) {
            f16x8 bfrag = Wb[(nt * 4 + ks) * 64 + lane];
            acc[nt] = __builtin_amdgcn_mfma_f32_16x16x32_f16(afrag, bfrag, acc[nt], 0, 0, 0);
        }
    }

#pragma unroll
    for (int nt = 0; nt < 16; ++nt) {
        int feat = nt * 16 + col;
        float b = s_bias[feat];
#pragma unroll
        for (int r = 0; r < 4; ++r) {
            int m = wave * 16 + kgrp * 4 + r;
            int n = n0 + m;
            if (n < N_NODES) UV[n * 256 + feat] = (_Float16)(acc[nt][r] + b);
        }
    }
}

// ===========================================================================
// Edge predictor, LDS-free, CSR(dst-sorted) order:
// out[eid] = relu(U[src] + V[dst]) @ Wp2 + bp2.
// Wave = 2 edge slots x 32 lanes x 4 feats; 4-deep unroll -> 8 edges/wave.
// N_EDGES = 32 * 18750 exactly.
// ===========================================================================
__global__ __launch_bounds__(256) void edge_pred_kernel(
        const _Float16* __restrict__ UV,
        const int2* __restrict__ pk,
        const int* __restrict__ pdst,
        const float* __restrict__ Wp2,
        const float* __restrict__ bp2,
        float* __restrict__ out) {
    int t = threadIdx.x;
    int wave = t >> 6;
    int lane = t & 63;
    int slot = lane >> 5;
    int k4 = (lane & 31) * 4;

    // per-lane constants: Wp2 rows k4..k4+3 (interleaved c0/c1), bp2
    float4 wa = *(const float4*)&Wp2[k4 * 2];       // w[k4][0],w[k4][1],w[k4+1][0],w[k4+1][1]
    float4 wb = *(const float4*)&Wp2[k4 * 2 + 4];   // w[k4+2][0..1],w[k4+3][0..1]
    float b0 = bp2[0], b1 = bp2[1];

    int e0 = blockIdx.x * 32 + wave * 8;

    int2 pv[4];
    int dn[4];
#pragma unroll
    for (int u = 0; u < 4; ++u) {
        int pos = e0 + 2 * u + slot;
        pv[u] = pk[pos];
        dn[u] = pdst[pos];
    }
    f16x4 uu[4], vv[4];
#pragma unroll
    for (int u = 0; u < 4; ++u) {
        uu[u] = *(const f16x4*)&UV[pv[u].x * 256 + k4];
        vv[u] = *(const f16x4*)&UV[dn[u] * 256 + 128 + k4];
    }

    float p0[4], p1[4];
#pragma unroll
    for (int u = 0; u < 4; ++u) {
        float z0 = (float)uu[u].x + (float)vv[u].x; z0 = z0 > 0.f ? z0 : 0.f;
        float z1 = (float)uu[u].y + (float)vv[u].y; z1 = z1 > 0.f ? z1 : 0.f;
        float z2 = (float)uu[u].z + (float)vv[u].z; z2 = z2 > 0.f ? z2 : 0.f;
        float z3 = (float)uu[u].w + (float)vv[u].w; z3 = z3 > 0.f ? z3 : 0.f;
        p0[u] = z0 * wa.x + z1 * wa.z + z2 * wb.x + z3 * wb.z;
        p1[u] = z0 * wa.y + z1 * wa.w + z2 * wb.y + z3 * wb.w;
    }
#pragma unroll
    for (int m = 1; m < 32; m <<= 1) {
#pragma unroll
        for (int u = 0; u < 4; ++u) {
            p0[u] += __shfl_xor(p0[u], m);
            p1[u] += __shfl_xor(p1[u], m);
        }
    }
    if ((lane & 31) == 0) {
#pragma unroll
        for (int u = 0; u < 4; ++u) {
            float2 o;
            o.x = p0[u] + b0;
            o.y = p1[u] + b1;
            *(float2*)&out[pv[u].y * 2] = o;
        }
    }
}

// ===========================================================================
extern "C" void kernel_launch(void* const* d_in, const int* in_sizes, int n_in,
                              void* d_out, int out_size, void* d_ws, size_t ws_size,
                              hipStream_t stream) {
    const float* x   = (const float*)d_in[0];
    const int*   ei  = (const int*)d_in[1];
    const float* ea  = (const float*)d_in[2];
    const float* We1 = (const float*)d_in[3];
    const float* be1 = (const float*)d_in[4];
    const float* Wl1 = (const float*)d_in[5];
    const float* bl1 = (const float*)d_in[6];
    const float* Wr1 = (const float*)d_in[7];
    const float* br1 = (const float*)d_in[8];
    const float* We2 = (const float*)d_in[9];
    const float* be2 = (const float*)d_in[10];
    const float* Wl2 = (const float*)d_in[11];
    const float* bl2 = (const float*)d_in[12];
    const float* Wr2 = (const float*)d_in[13];
    const float* br2 = (const float*)d_in[14];
    const float* Wp1 = (const float*)d_in[15];
    const float* bp1 = (const float*)d_in[16];
    const float* Wp2 = (const float*)d_in[17];
    const float* bp2 = (const float*)d_in[18];
    float* out = (float*)d_out;

    const int* src = ei;
    const int* dst = ei + N_EDGES;

    char* ws = (char*)d_ws;
    int*   cnt     = (int*)(ws + 0);           // 409600
    int*   scanout = (int*)(ws + 409600);      // 409600
    int*   bsum    = (int*)(ws + 819200);      // 8192
    int*   rowptr  = (int*)(ws + 827392);      // 409600 (N+1 ints)
    int*   cur     = (int*)(ws + 1236992);     // 409600
    int2*  pk      = (int2*)(ws + 1646592);    // 4800512
    float* WeWl1   = (float*)(ws + 6447104);   // 16384
    float* beWl1   = (float*)(ws + 6463488);   // 512
    float* WeWl2   = (float*)(ws + 6464000);   // 16384
    float* beWl2   = (float*)(ws + 6480384);   // 512
    _Float16* eamb = (_Float16*)(ws + 6480896);   // 6.4 MB
    _Float16* xb   = (_Float16*)(ws + 12880896);  // 25.6 MB
    _Float16* meanb= (_Float16*)(ws + 38480896);  // 25.6 MB
    // UV (51.2 MB) aliases xb+meanb (both dead before uv_gemm)
    _Float16* UV   = (_Float16*)(ws + 12880896);
    _Float16* h1b  = (_Float16*)(ws + 64080896);  // 25.6 MB
    _Float16* h2b  = (_Float16*)(ws + 89680896);  // 25.6 MB
    _Float16* Wbs1 = (_Float16*)(ws + 115280896); // 73728
    _Float16* Wbs2 = (_Float16*)(ws + 115354624); // 73728
    _Float16* Wuv  = (_Float16*)(ws + 115428352); // 65536
    int*   pdst    = (int*)(ws + 115493888);      // 2.4 MB

    const int EB = (N_EDGES + 255) / 256;

    // ---- CSR build ----
    hipMemsetAsync(cnt, 0, N_NODES * sizeof(int), stream);
    hist_kernel<<<EB, 256, 0, stream>>>(dst, cnt);
    scan1_kernel<<<NBLK, 256, 0, stream>>>(cnt, scanout, bsum);
    scan2_kernel<<<1, 512, 0, stream>>>(bsum);
    scan3_kernel<<<NBLK, 256, 0, stream>>>(cnt, scanout, bsum, rowptr, cur);
    fill_kernel<<<EB, 256, 0, stream>>>(src, dst, cur, pk, pdst);

    // ---- graph-invariant precompute ----
    eam_kernel<<<N_NODES / 32, 256, 0, stream>>>(rowptr, pk, ea, eamb);
    wewl_kernel<<<17, 256, 0, stream>>>(We1, be1, Wl1, WeWl1, beWl1);
    wewl_kernel<<<17, 256, 0, stream>>>(We2, be2, Wl2, WeWl2, beWl2);
    xb_kernel<<<(N_NODES * HIDDEN / 2 + 255) / 256, 256, 0, stream>>>(x, xb);
    wbig_swizzle_kernel<<<144, 256, 0, stream>>>(Wl1, Wr1, WeWl1, Wbs1);
    wbig_swizzle_kernel<<<144, 256, 0, stream>>>(Wl2, Wr2, WeWl2, Wbs2);
    wp1uv_swizzle_kernel<<<128, 256, 0, stream>>>(Wp1, Wuv);

    // ---- layer 1 ----
    agg_kernel<<<N_NODES / 32, 256, 0, stream>>>(xb, rowptr, pk, meanb);
    node_gemm_kernel<<<(N_NODES + 63) / 64, 256, 0, stream>>>(
        meanb, xb, eamb, Wbs1, rowptr, bl1, br1, beWl1, h1b);

    // ---- layer 2 ----
    agg_kernel<<<N_NODES / 32, 256, 0, stream>>>(h1b, rowptr, pk, meanb);
    node_gemm_kernel<<<(N_NODES + 63) / 64, 256, 0, stream>>>(
        meanb, h1b, eamb, Wbs2, rowptr, bl2, br2, beWl2, h2b);

    // ---- edge predictor: UV decomposition + streaming edge pass ----
    uv_gemm_kernel<<<(N_NODES + 63) / 64, 256, 0, stream>>>(h2b, Wuv, bp1, UV);
    edge_pred_kernel<<<N_EDGES / 32, 256, 0, stream>>>(UV, pk, pdst, Wp2, bp2, out);
}